// Round 10
// baseline (202.802 us; speedup 1.0000x reference)
//
#include <hip/hip_runtime.h>
#include <hip/hip_bf16.h>
#include <math.h>

typedef short s8v  __attribute__((ext_vector_type(8)));
typedef float f16v __attribute__((ext_vector_type(16)));

#define HH 256
#define TP 32              // points per block (one 32-row MFMA tile)
#define NTHREADS 256
#define SSTR 8192          // shorts per stream A-tile: 16 ksteps * 512 (16KB)
// A-plane: 3 streams * 16KB = 48KB. Layout: stream*SSTR + kstep*512 + lane*8
// where lane = point + 32*kchunk, elems j: feature n = kstep*16 + kchunk*8 + j.
// (32x32x16 bf16 fragment: row=lane&31, k = 8*(lane>>5)+j; any consistent
// k-permutation shared by A-scatter and B-prep is GEMM-invariant.)

__device__ __forceinline__ unsigned short bf_rne(float x){
    union{float f;unsigned u;}v; v.f=x;
    unsigned r = v.u + 0x7FFFu + ((v.u >> 16) & 1u);
    return (unsigned short)(r >> 16);
}
__device__ __forceinline__ unsigned pack_rne2(float a, float b){
    union { __hip_bfloat162 h; unsigned u; } v;
    v.h = __float22bfloat162_rn(float2{a, b});
    return v.u;
}

// ---- prep: B-fragments for W1..W3 in 32x32x16 layout, RAW-order fp32 planes
// for W0 cols / b0 / W4. B-frag (ct, kstep): lane holds W[ct*32 + (lane&31)]
// [kstep*16 + (lane>>5)*8 + j]  ->  wsB[layer*65536 + ct*8192 + kstep*512 + lane*8 + j]
__global__ __launch_bounds__(256)
void prep_weights(const float* __restrict__ W1, const float* __restrict__ W2,
                  const float* __restrict__ W3, const float* __restrict__ W0,
                  const float* __restrict__ b0, const float* __restrict__ W4,
                  unsigned short* __restrict__ wsB, float* __restrict__ wsF)
{
    int t = blockIdx.x * 256 + threadIdx.x;
    if (t < 24576) {
        int layer = t >> 13;            // 0..2
        int rem   = t & 8191;
        int lane  = rem & 63;
        int kstep = (rem >> 6) & 15;
        int ct    = rem >> 10;          // 0..7
        const float* W = (layer == 0) ? W1 : (layer == 1) ? W2 : W3;
        int row  = ct * 32 + (lane & 31);
        int nin0 = kstep * 16 + (lane >> 5) * 8;
        const float* src = W + row * HH + nin0;
        s8v hi;
        #pragma unroll
        for (int j = 0; j < 8; ++j) hi[j] = (short)bf_rne(src[j]);
        int dst = layer * 65536 + ct * 8192 + kstep * 512 + lane * 8;
        *(s8v*)(wsB + dst) = hi;
    } else if (t < 24832) {
        int n = t - 24576;              // RAW order now (no pi permutation)
        wsF[n]       = W0[2 * n];
        wsF[256 + n] = W0[2 * n + 1];
        wsF[512 + n] = b0[n];
        wsF[768 + n] = W4[n];
    }
}

// ---- MFMA one layer: 16 ksteps x (3 A ds_reads + 2 B loads + 6 MFMA).
// Wlh pre-offset to this wave's first col-tile (ct = 2w).
__device__ __forceinline__ void mfma_layer32(
    f16v (&acc)[3][2], const unsigned short* Ahi,
    const unsigned short* __restrict__ Wlh,
    float biasA, float biasB, int lane)
{
    #pragma unroll
    for (int r = 0; r < 16; ++r) {
        acc[0][0][r] = biasA; acc[0][1][r] = biasB;
        acc[1][0][r] = 0.f;   acc[1][1][r] = 0.f;
        acc[2][0][r] = 0.f;   acc[2][1][r] = 0.f;
    }
    __builtin_amdgcn_s_setprio(1);
    #pragma unroll
    for (int k = 0; k < 16; ++k) {
        const int ab = k * 512 + lane * 8;
        s8v a0 = *(const s8v*)&Ahi[ab];
        s8v a1 = *(const s8v*)&Ahi[SSTR + ab];
        s8v a2 = *(const s8v*)&Ahi[2 * SSTR + ab];
        s8v b0 = *(const s8v*)&Wlh[ab];
        s8v b1 = *(const s8v*)&Wlh[8192 + ab];
        acc[0][0] = __builtin_amdgcn_mfma_f32_32x32x16_bf16(a0, b0, acc[0][0], 0, 0, 0);
        acc[1][0] = __builtin_amdgcn_mfma_f32_32x32x16_bf16(a1, b0, acc[1][0], 0, 0, 0);
        acc[2][0] = __builtin_amdgcn_mfma_f32_32x32x16_bf16(a2, b0, acc[2][0], 0, 0, 0);
        acc[0][1] = __builtin_amdgcn_mfma_f32_32x32x16_bf16(a0, b1, acc[0][1], 0, 0, 0);
        acc[1][1] = __builtin_amdgcn_mfma_f32_32x32x16_bf16(a1, b1, acc[1][1], 0, 0, 0);
        acc[2][1] = __builtin_amdgcn_mfma_f32_32x32x16_bf16(a2, b1, acc[2][1], 0, 0, 0);
    }
    __builtin_amdgcn_s_setprio(0);
}

// ---- transform: C/D (col=lane&31 -> feature, row=(reg&3)+8*(reg>>2)+4*half
// -> point) -> tanh chain -> bf16 b16-scatter into the A-plane for next layer.
__device__ __forceinline__ void transform32(
    f16v (&acc)[3][2], unsigned short* Ahi, int w, int lane)
{
    const int col = lane & 31, half = lane >> 5;
    #pragma unroll
    for (int cti = 0; cti < 2; ++cti) {
        const int kst   = (2 * w + cti) * 2 + (col >> 4);
        const int basec = kst * 512 + ((col >> 3) & 1) * 256 + (col & 7);
        #pragma unroll
        for (int reg = 0; reg < 16; ++reg) {
            const int rP = (reg & 3) + 8 * (reg >> 2) + 4 * half;
            float z  = acc[0][cti][reg];
            float z1 = acc[1][cti][reg];
            float z2 = acc[2][cti][reg];
            float e  = __expf(2.f * z);
            float a  = 1.f - 2.f * __builtin_amdgcn_rcpf(e + 1.f);
            float g  = 1.f - a * a;
            float d1 = g * z1;
            float d2 = fmaf(g, z2, -2.f * a * d1 * z1);
            const int sa = basec + rP * 8;
            Ahi[sa]            = bf_rne(a);
            Ahi[SSTR + sa]     = bf_rne(d1);
            Ahi[2 * SSTR + sa] = bf_rne(d2);
        }
    }
}

// ---- fused head: per-reg transform + W4 dot + 32-lane column reduce ----
__device__ __forceinline__ void head32(
    f16v (&acc)[3][2], const float* __restrict__ wsF,
    float* head_part, int w, int lane)
{
    const int col = lane & 31, half = lane >> 5;
    const float w4a = wsF[768 + (2 * w) * 32 + col];
    const float w4b = wsF[768 + (2 * w + 1) * 32 + col];
    #pragma unroll
    for (int reg = 0; reg < 16; ++reg) {
        float ha = 0.f, h1 = 0.f, h2 = 0.f;
        #pragma unroll
        for (int cti = 0; cti < 2; ++cti) {
            float z  = acc[0][cti][reg];
            float z1 = acc[1][cti][reg];
            float z2 = acc[2][cti][reg];
            float e  = __expf(2.f * z);
            float a  = 1.f - 2.f * __builtin_amdgcn_rcpf(e + 1.f);
            float g  = 1.f - a * a;
            float d1 = g * z1;
            float d2 = fmaf(g, z2, -2.f * a * d1 * z1);
            float w4 = cti ? w4b : w4a;
            ha = fmaf(w4, a, ha); h1 = fmaf(w4, d1, h1); h2 = fmaf(w4, d2, h2);
        }
        #pragma unroll
        for (int m = 1; m < 32; m <<= 1) {   // reduce over the 32-col group
            ha += __shfl_xor(ha, m);
            h1 += __shfl_xor(h1, m);
            h2 += __shfl_xor(h2, m);
        }
        if (col == 0) {
            const int rP = (reg & 3) + 8 * (reg >> 2) + 4 * half;
            head_part[(0 * TP + rP) * 4 + w] = ha;
            head_part[(1 * TP + rP) * 4 + w] = h1;
            head_part[(2 * TP + rP) * 4 + w] = h2;
        }
    }
}

// ---- main fused kernel: 32x32x16 MFMA (m119: 2495 vs 2176 TF for 16x16,
// +15% shape throughput, half the loop instructions per FLOP). TP=32, 4
// waves x 2 col-tiles, acc[3][2] f32x16 = 96 regs. LDS 48KB plane -> clean
// 3 blocks/CU uniform (R8's ragged 1.55 residency was part of the idle).
__global__ __launch_bounds__(NTHREADS, 3)
void capnn_mfma(const float* __restrict__ inp,
                const float* __restrict__ b1, const float* __restrict__ b2,
                const float* __restrict__ b3, const float* __restrict__ b4,
                const float* __restrict__ W4raw,
                const float* __restrict__ lgr, const float* __restrict__ lcc,
                const float* __restrict__ lil,
                const float* __restrict__ imean, const float* __restrict__ istd,
                const float* __restrict__ tmean, const float* __restrict__ tstd,
                const unsigned short* __restrict__ wsW,
                const float* __restrict__ wsF,
                float* __restrict__ out, int N)
{
    __shared__ __align__(16) unsigned short Ahi[3 * SSTR];   // 48 KB
    __shared__ float sn_sh[TP], tn_sh[TP];
    __shared__ float head_part[TP * 3 * 4];

    const int tid  = threadIdx.x;
    const int lane = tid & 63;
    const int w    = tid >> 6;          // 0..3: col-tile pair (2w, 2w+1)
    const int col  = lane & 31;
    const int pbase = blockIdx.x * TP;

    if (tid < TP) {
        int pg = pbase + tid;
        float s = 0.f, t = 0.f;
        if (pg < N) { s = inp[2 * pg]; t = inp[2 * pg + 1]; }
        sn_sh[tid] = (s - imean[0]) / (istd[0] + 1e-8f);
        tn_sh[tid] = (t - imean[1]) / (istd[1] + 1e-8f);
    }
    __syncthreads();                                    // B1

    // ---- layer 0 -> A-plane: lane = (p, kchunk c); wave w fills ksteps w+4g
    {
        const int p = lane & 31, c = lane >> 5;
        const float sn = sn_sh[p], tn = tn_sh[p];
        #pragma unroll
        for (int g = 0; g < 4; ++g) {
            const int m  = w + 4 * g;       // kstep
            const int nb = m * 16 + c * 8;  // first feature of this octet
            float4 wa0 = *(const float4*)(wsF + nb);
            float4 wa1 = *(const float4*)(wsF + nb + 4);
            float4 wb0 = *(const float4*)(wsF + 256 + nb);
            float4 wb1 = *(const float4*)(wsF + 256 + nb + 4);
            float4 bb0 = *(const float4*)(wsF + 512 + nb);
            float4 bb1 = *(const float4*)(wsF + 512 + nb + 4);
            float w00v[8] = {wa0.x,wa0.y,wa0.z,wa0.w,wa1.x,wa1.y,wa1.z,wa1.w};
            float w01v[8] = {wb0.x,wb0.y,wb0.z,wb0.w,wb1.x,wb1.y,wb1.z,wb1.w};
            float b0v[8]  = {bb0.x,bb0.y,bb0.z,bb0.w,bb1.x,bb1.y,bb1.z,bb1.w};
            float av[8], d1v[8], d2v[8];
            #pragma unroll
            for (int j = 0; j < 8; ++j) {
                float z = fmaf(w00v[j], sn, fmaf(w01v[j], tn, b0v[j]));
                float e = __expf(2.f * z);
                float a = 1.f - 2.f * __builtin_amdgcn_rcpf(e + 1.f);
                float g2 = 1.f - a * a;
                float d1 = g2 * w01v[j];
                float d2 = -2.f * a * d1 * w01v[j];
                av[j] = a; d1v[j] = d1; d2v[j] = d2;
            }
            const int base = m * 512 + lane * 8;
            #pragma unroll
            for (int s = 0; s < 3; ++s) {
                const float* V = (s == 0) ? av : (s == 1) ? d1v : d2v;
                int4 hi4;
                hi4.x = (int)pack_rne2(V[0], V[1]);
                hi4.y = (int)pack_rne2(V[2], V[3]);
                hi4.z = (int)pack_rne2(V[4], V[5]);
                hi4.w = (int)pack_rne2(V[6], V[7]);
                *(int4*)&Ahi[s * SSTR + base] = hi4;
            }
        }
    }
    __syncthreads();                                    // B2

    f16v acc[3][2];

    // L1
    mfma_layer32(acc, Ahi, wsW + (2 * w) * 8192,
                 b1[(2 * w) * 32 + col], b1[(2 * w + 1) * 32 + col], lane);
    __syncthreads();                                    // B3 (reads done)
    transform32(acc, Ahi, w, lane);
    __syncthreads();                                    // B4 (writes done)

    // L2
    mfma_layer32(acc, Ahi, wsW + 65536 + (2 * w) * 8192,
                 b2[(2 * w) * 32 + col], b2[(2 * w + 1) * 32 + col], lane);
    __syncthreads();                                    // B5
    transform32(acc, Ahi, w, lane);
    __syncthreads();                                    // B6

    // L3 + fused head
    mfma_layer32(acc, Ahi, wsW + 131072 + (2 * w) * 8192,
                 b3[(2 * w) * 32 + col], b3[(2 * w + 1) * 32 + col], lane);
    head32(acc, wsF, head_part, w, lane);
    __syncthreads();                                    // B7

    // ---- Verhulst residuals + store ----
    if (tid < TP) {
        float sv = 0.f, s1v = 0.f, s2v = 0.f;
        #pragma unroll
        for (int ww = 0; ww < 4; ++ww) {
            sv  += head_part[(0 * TP + tid) * 4 + ww];
            s1v += head_part[(1 * TP + tid) * 4 + ww];
            s2v += head_part[(2 * TP + tid) * 4 + ww];
        }
        int pg = pbase + tid;
        if (pg < N) {
            float r_  = expf(-lgr[0]);
            float Kc  = 0.2f + 0.8f / (1.f + expf(-lcc[0]));
            float Cc  = 0.1f / (1.f + expf(-lil[0]));
            float kci = 1.f / (Kc - Cc);
            float ts = tstd[0], tm = tmean[0];
            float U   = (sv + b4[0]) * ts + tm;
            float Ut  = s1v * ts;
            float Utt = s2v * ts;
            float Um  = U - Cc;
            float G   = r_ * Um * (1.f - Um * kci);
            float Gt  = r_ * Ut * (1.f - 2.f * Um * kci);
            out[pg]         = U;
            out[N + pg]     = Ut - G;
            out[2 * N + pg] = Utt - Gt;
        }
    }
}

extern "C" void kernel_launch(void* const* d_in, const int* in_sizes, int n_in,
                              void* d_out, int out_size, void* d_ws, size_t ws_size,
                              hipStream_t stream) {
    const float* inp   = (const float*)d_in[0];
    const float* W0    = (const float*)d_in[1];
    const float* b0    = (const float*)d_in[2];
    const float* W1    = (const float*)d_in[3];
    const float* b1    = (const float*)d_in[4];
    const float* W2    = (const float*)d_in[5];
    const float* b2    = (const float*)d_in[6];
    const float* W3    = (const float*)d_in[7];
    const float* b3    = (const float*)d_in[8];
    const float* W4    = (const float*)d_in[9];
    const float* b4    = (const float*)d_in[10];
    const float* lgr   = (const float*)d_in[11];
    const float* lcc   = (const float*)d_in[12];
    const float* lil   = (const float*)d_in[13];
    const float* imean = (const float*)d_in[14];
    const float* istd  = (const float*)d_in[15];
    const float* tmean = (const float*)d_in[16];
    const float* tstd  = (const float*)d_in[17];

    unsigned short* wsB = (unsigned short*)d_ws;            // 384 KB B-frags (RNE bf16)
    float* wsF = (float*)((char*)d_ws + 393216);            // 4 KB raw planes

    const int N = in_sizes[0] / 2;
    const int gridMain = (N + TP - 1) / TP;                 // 2048 blocks

    hipLaunchKernelGGL(prep_weights, dim3(97), dim3(256), 0, stream,
                       W1, W2, W3, W0, b0, W4, wsB, wsF);
    hipLaunchKernelGGL(capnn_mfma, dim3(gridMain), dim3(NTHREADS), 0, stream,
                       inp, b1, b2, b3, b4, W4,
                       lgr, lcc, lil, imean, istd, tmean, tstd,
                       wsB, wsF, (float*)d_out, N);
}

// Round 11
// 191.902 us; speedup vs baseline: 1.0568x; 1.0568x over previous
//
#include <hip/hip_runtime.h>
#include <hip/hip_bf16.h>
#include <math.h>

typedef short s8v  __attribute__((ext_vector_type(8)));
typedef float f16v __attribute__((ext_vector_type(16)));

#define HH 256
#define TP 32              // points per block (one 32-row MFMA tile)
#define NTHREADS 256
// Padded A-plane strides (in SHORTS) — R10 had c-stride 256 / kstep-stride 512
// (both bank-aligned -> 8-way conflicts on the b16 transform scatter, 9.4M
// conflict cycles). 264/536 shift the col-groups to banks {0-3},{4-7},
// {12-15},{16-19} (half2 +16) -> worst 2-way = free. b128 reads remain two
// contiguous 512B runs per half-wave -> conflict-free.
#define CSS 264            // k-half (c) stride
#define KSS 536            // kstep stride = 2*CSS + 8
#define SSTR (16 * KSS)    // stream stride: 8576 shorts (17.2 KB)
// Plane: 3 streams * 17.2 KB = 51.5 KB -> 2 blocks/CU with the 256-reg budget.
// Layout: stream*SSTR + kstep*KSS + p*8 + c*CSS + j, lane = p + 32c,
// feature n = kstep*16 + c*8 + j. (32x32x16 bf16 frag: row=lane&31,
// k = 8*(lane>>5)+j; shared k-permutation in A and B is GEMM-invariant —
// verified correct in R10, absmax unchanged.)

__device__ __forceinline__ unsigned short bf_rne(float x){
    union{float f;unsigned u;}v; v.f=x;
    unsigned r = v.u + 0x7FFFu + ((v.u >> 16) & 1u);
    return (unsigned short)(r >> 16);
}
__device__ __forceinline__ unsigned pack_rne2(float a, float b){
    union { __hip_bfloat162 h; unsigned u; } v;
    v.h = __float22bfloat162_rn(float2{a, b});
    return v.u;
}

// ---- prep: B-fragments for W1..W3 in 32x32x16 layout (dense, global mem),
// RAW-order fp32 planes for W0 cols / b0 / W4.  (unchanged from R10)
__global__ __launch_bounds__(256)
void prep_weights(const float* __restrict__ W1, const float* __restrict__ W2,
                  const float* __restrict__ W3, const float* __restrict__ W0,
                  const float* __restrict__ b0, const float* __restrict__ W4,
                  unsigned short* __restrict__ wsB, float* __restrict__ wsF)
{
    int t = blockIdx.x * 256 + threadIdx.x;
    if (t < 24576) {
        int layer = t >> 13;            // 0..2
        int rem   = t & 8191;
        int lane  = rem & 63;
        int kstep = (rem >> 6) & 15;
        int ct    = rem >> 10;          // 0..7
        const float* W = (layer == 0) ? W1 : (layer == 1) ? W2 : W3;
        int row  = ct * 32 + (lane & 31);
        int nin0 = kstep * 16 + (lane >> 5) * 8;
        const float* src = W + row * HH + nin0;
        s8v hi;
        #pragma unroll
        for (int j = 0; j < 8; ++j) hi[j] = (short)bf_rne(src[j]);
        int dst = layer * 65536 + ct * 8192 + kstep * 512 + lane * 8;
        *(s8v*)(wsB + dst) = hi;
    } else if (t < 24832) {
        int n = t - 24576;              // RAW order (no permutation)
        wsF[n]       = W0[2 * n];
        wsF[256 + n] = W0[2 * n + 1];
        wsF[512 + n] = b0[n];
        wsF[768 + n] = W4[n];
    }
}

// ---- MFMA one layer: 16 ksteps x (3 A ds_reads + 2 B loads + 6 MFMA).
__device__ __forceinline__ void mfma_layer32(
    f16v (&acc)[3][2], const unsigned short* Ahi,
    const unsigned short* __restrict__ Wlh,
    float biasA, float biasB, int laneoff, int lane)
{
    #pragma unroll
    for (int r = 0; r < 16; ++r) {
        acc[0][0][r] = biasA; acc[0][1][r] = biasB;
        acc[1][0][r] = 0.f;   acc[1][1][r] = 0.f;
        acc[2][0][r] = 0.f;   acc[2][1][r] = 0.f;
    }
    __builtin_amdgcn_s_setprio(1);
    #pragma unroll
    for (int k = 0; k < 16; ++k) {
        const int ab = k * KSS + laneoff;          // padded A addressing
        const int bb = k * 512 + lane * 8;         // dense B (global)
        s8v a0 = *(const s8v*)&Ahi[ab];
        s8v a1 = *(const s8v*)&Ahi[SSTR + ab];
        s8v a2 = *(const s8v*)&Ahi[2 * SSTR + ab];
        s8v b0 = *(const s8v*)&Wlh[bb];
        s8v b1 = *(const s8v*)&Wlh[8192 + bb];
        acc[0][0] = __builtin_amdgcn_mfma_f32_32x32x16_bf16(a0, b0, acc[0][0], 0, 0, 0);
        acc[1][0] = __builtin_amdgcn_mfma_f32_32x32x16_bf16(a1, b0, acc[1][0], 0, 0, 0);
        acc[2][0] = __builtin_amdgcn_mfma_f32_32x32x16_bf16(a2, b0, acc[2][0], 0, 0, 0);
        acc[0][1] = __builtin_amdgcn_mfma_f32_32x32x16_bf16(a0, b1, acc[0][1], 0, 0, 0);
        acc[1][1] = __builtin_amdgcn_mfma_f32_32x32x16_bf16(a1, b1, acc[1][1], 0, 0, 0);
        acc[2][1] = __builtin_amdgcn_mfma_f32_32x32x16_bf16(a2, b1, acc[2][1], 0, 0, 0);
    }
    __builtin_amdgcn_s_setprio(0);
}

// ---- transform: C/D (col=lane&31 -> feature, row=(reg&3)+8*(reg>>2)+4*half
// -> point) -> tanh chain -> bf16 b16-scatter into the padded A-plane.
__device__ __forceinline__ void transform32(
    f16v (&acc)[3][2], unsigned short* Ahi, int w, int lane)
{
    const int col = lane & 31, half = lane >> 5;
    #pragma unroll
    for (int cti = 0; cti < 2; ++cti) {
        const int kst   = (2 * w + cti) * 2 + (col >> 4);
        const int basec = kst * KSS + ((col >> 3) & 1) * CSS + (col & 7);
        #pragma unroll
        for (int reg = 0; reg < 16; ++reg) {
            const int rP = (reg & 3) + 8 * (reg >> 2) + 4 * half;
            float z  = acc[0][cti][reg];
            float z1 = acc[1][cti][reg];
            float z2 = acc[2][cti][reg];
            float e  = __expf(2.f * z);
            float a  = 1.f - 2.f * __builtin_amdgcn_rcpf(e + 1.f);
            float g  = 1.f - a * a;
            float d1 = g * z1;
            float d2 = fmaf(g, z2, -2.f * a * d1 * z1);
            const int sa = basec + rP * 8;
            Ahi[sa]            = bf_rne(a);
            Ahi[SSTR + sa]     = bf_rne(d1);
            Ahi[2 * SSTR + sa] = bf_rne(d2);
        }
    }
}

// ---- fused head: per-reg transform + W4 dot + 32-lane column reduce ----
__device__ __forceinline__ void head32(
    f16v (&acc)[3][2], const float* __restrict__ wsF,
    float* head_part, int w, int lane)
{
    const int col = lane & 31, half = lane >> 5;
    const float w4a = wsF[768 + (2 * w) * 32 + col];
    const float w4b = wsF[768 + (2 * w + 1) * 32 + col];
    #pragma unroll
    for (int reg = 0; reg < 16; ++reg) {
        float ha = 0.f, h1 = 0.f, h2 = 0.f;
        #pragma unroll
        for (int cti = 0; cti < 2; ++cti) {
            float z  = acc[0][cti][reg];
            float z1 = acc[1][cti][reg];
            float z2 = acc[2][cti][reg];
            float e  = __expf(2.f * z);
            float a  = 1.f - 2.f * __builtin_amdgcn_rcpf(e + 1.f);
            float g  = 1.f - a * a;
            float d1 = g * z1;
            float d2 = fmaf(g, z2, -2.f * a * d1 * z1);
            float w4 = cti ? w4b : w4a;
            ha = fmaf(w4, a, ha); h1 = fmaf(w4, d1, h1); h2 = fmaf(w4, d2, h2);
        }
        #pragma unroll
        for (int m = 1; m < 32; m <<= 1) {   // reduce over the 32-col group
            ha += __shfl_xor(ha, m);
            h1 += __shfl_xor(h1, m);
            h2 += __shfl_xor(h2, m);
        }
        if (col == 0) {
            const int rP = (reg & 3) + 8 * (reg >> 2) + 4 * half;
            head_part[(0 * TP + rP) * 4 + w] = ha;
            head_part[(1 * TP + rP) * 4 + w] = h1;
            head_part[(2 * TP + rP) * 4 + w] = h2;
        }
    }
}

// ---- main fused kernel: 32x32x16 MFMA, spill-free + conflict-free redo of
// R10. launch_bounds(256,2): 256-reg budget holds acc 96 + ~120 VGPR with NO
// spill (R10: (256,3) cap 170 < 180 live -> 86MB scratch). Padded strides
// kill the 9.4M-cycle scatter conflicts. 2 blocks/CU (R8-equal residency).
__global__ __launch_bounds__(NTHREADS, 2)
void capnn_mfma(const float* __restrict__ inp,
                const float* __restrict__ b1, const float* __restrict__ b2,
                const float* __restrict__ b3, const float* __restrict__ b4,
                const float* __restrict__ W4raw,
                const float* __restrict__ lgr, const float* __restrict__ lcc,
                const float* __restrict__ lil,
                const float* __restrict__ imean, const float* __restrict__ istd,
                const float* __restrict__ tmean, const float* __restrict__ tstd,
                const unsigned short* __restrict__ wsW,
                const float* __restrict__ wsF,
                float* __restrict__ out, int N)
{
    __shared__ __align__(16) unsigned short Ahi[3 * SSTR];   // 51.5 KB
    __shared__ float sn_sh[TP], tn_sh[TP];
    __shared__ float head_part[TP * 3 * 4];

    const int tid  = threadIdx.x;
    const int lane = tid & 63;
    const int w    = tid >> 6;          // 0..3: col-tile pair (2w, 2w+1)
    const int col  = lane & 31;
    const int laneoff = (lane & 31) * 8 + (lane >> 5) * CSS;
    const int pbase = blockIdx.x * TP;

    if (tid < TP) {
        int pg = pbase + tid;
        float s = 0.f, t = 0.f;
        if (pg < N) { s = inp[2 * pg]; t = inp[2 * pg + 1]; }
        sn_sh[tid] = (s - imean[0]) / (istd[0] + 1e-8f);
        tn_sh[tid] = (t - imean[1]) / (istd[1] + 1e-8f);
    }
    __syncthreads();                                    // B1

    // ---- layer 0 -> A-plane: lane = (p, kchunk c); wave w fills ksteps w+4g
    {
        const int p = lane & 31, c = lane >> 5;
        const float sn = sn_sh[p], tn = tn_sh[p];
        #pragma unroll
        for (int g = 0; g < 4; ++g) {
            const int m  = w + 4 * g;       // kstep
            const int nb = m * 16 + c * 8;  // first feature of this octet
            float4 wa0 = *(const float4*)(wsF + nb);
            float4 wa1 = *(const float4*)(wsF + nb + 4);
            float4 wb0 = *(const float4*)(wsF + 256 + nb);
            float4 wb1 = *(const float4*)(wsF + 256 + nb + 4);
            float4 bb0 = *(const float4*)(wsF + 512 + nb);
            float4 bb1 = *(const float4*)(wsF + 512 + nb + 4);
            float w00v[8] = {wa0.x,wa0.y,wa0.z,wa0.w,wa1.x,wa1.y,wa1.z,wa1.w};
            float w01v[8] = {wb0.x,wb0.y,wb0.z,wb0.w,wb1.x,wb1.y,wb1.z,wb1.w};
            float b0v[8]  = {bb0.x,bb0.y,bb0.z,bb0.w,bb1.x,bb1.y,bb1.z,bb1.w};
            float av[8], d1v[8], d2v[8];
            #pragma unroll
            for (int j = 0; j < 8; ++j) {
                float z = fmaf(w00v[j], sn, fmaf(w01v[j], tn, b0v[j]));
                float e = __expf(2.f * z);
                float a = 1.f - 2.f * __builtin_amdgcn_rcpf(e + 1.f);
                float g2 = 1.f - a * a;
                float d1 = g2 * w01v[j];
                float d2 = -2.f * a * d1 * w01v[j];
                av[j] = a; d1v[j] = d1; d2v[j] = d2;
            }
            const int base = m * KSS + laneoff;
            #pragma unroll
            for (int s = 0; s < 3; ++s) {
                const float* V = (s == 0) ? av : (s == 1) ? d1v : d2v;
                int4 hi4;
                hi4.x = (int)pack_rne2(V[0], V[1]);
                hi4.y = (int)pack_rne2(V[2], V[3]);
                hi4.z = (int)pack_rne2(V[4], V[5]);
                hi4.w = (int)pack_rne2(V[6], V[7]);
                *(int4*)&Ahi[s * SSTR + base] = hi4;
            }
        }
    }
    __syncthreads();                                    // B2

    f16v acc[3][2];

    // L1
    mfma_layer32(acc, Ahi, wsW + (2 * w) * 8192,
                 b1[(2 * w) * 32 + col], b1[(2 * w + 1) * 32 + col], laneoff, lane);
    __syncthreads();                                    // B3 (reads done)
    transform32(acc, Ahi, w, lane);
    __syncthreads();                                    // B4 (writes done)

    // L2
    mfma_layer32(acc, Ahi, wsW + 65536 + (2 * w) * 8192,
                 b2[(2 * w) * 32 + col], b2[(2 * w + 1) * 32 + col], laneoff, lane);
    __syncthreads();                                    // B5
    transform32(acc, Ahi, w, lane);
    __syncthreads();                                    // B6

    // L3 + fused head
    mfma_layer32(acc, Ahi, wsW + 131072 + (2 * w) * 8192,
                 b3[(2 * w) * 32 + col], b3[(2 * w + 1) * 32 + col], laneoff, lane);
    head32(acc, wsF, head_part, w, lane);
    __syncthreads();                                    // B7

    // ---- Verhulst residuals + store ----
    if (tid < TP) {
        float sv = 0.f, s1v = 0.f, s2v = 0.f;
        #pragma unroll
        for (int ww = 0; ww < 4; ++ww) {
            sv  += head_part[(0 * TP + tid) * 4 + ww];
            s1v += head_part[(1 * TP + tid) * 4 + ww];
            s2v += head_part[(2 * TP + tid) * 4 + ww];
        }
        int pg = pbase + tid;
        if (pg < N) {
            float r_  = expf(-lgr[0]);
            float Kc  = 0.2f + 0.8f / (1.f + expf(-lcc[0]));
            float Cc  = 0.1f / (1.f + expf(-lil[0]));
            float kci = 1.f / (Kc - Cc);
            float ts = tstd[0], tm = tmean[0];
            float U   = (sv + b4[0]) * ts + tm;
            float Ut  = s1v * ts;
            float Utt = s2v * ts;
            float Um  = U - Cc;
            float G   = r_ * Um * (1.f - Um * kci);
            float Gt  = r_ * Ut * (1.f - 2.f * Um * kci);
            out[pg]         = U;
            out[N + pg]     = Ut - G;
            out[2 * N + pg] = Utt - Gt;
        }
    }
}

extern "C" void kernel_launch(void* const* d_in, const int* in_sizes, int n_in,
                              void* d_out, int out_size, void* d_ws, size_t ws_size,
                              hipStream_t stream) {
    const float* inp   = (const float*)d_in[0];
    const float* W0    = (const float*)d_in[1];
    const float* b0    = (const float*)d_in[2];
    const float* W1    = (const float*)d_in[3];
    const float* b1    = (const float*)d_in[4];
    const float* W2    = (const float*)d_in[5];
    const float* b2    = (const float*)d_in[6];
    const float* W3    = (const float*)d_in[7];
    const float* b3    = (const float*)d_in[8];
    const float* W4    = (const float*)d_in[9];
    const float* b4    = (const float*)d_in[10];
    const float* lgr   = (const float*)d_in[11];
    const float* lcc   = (const float*)d_in[12];
    const float* lil   = (const float*)d_in[13];
    const float* imean = (const float*)d_in[14];
    const float* istd  = (const float*)d_in[15];
    const float* tmean = (const float*)d_in[16];
    const float* tstd  = (const float*)d_in[17];

    unsigned short* wsB = (unsigned short*)d_ws;            // 384 KB B-frags (RNE bf16)
    float* wsF = (float*)((char*)d_ws + 393216);            // 4 KB raw planes

    const int N = in_sizes[0] / 2;
    const int gridMain = (N + TP - 1) / TP;                 // 2048 blocks

    hipLaunchKernelGGL(prep_weights, dim3(97), dim3(256), 0, stream,
                       W1, W2, W3, W0, b0, W4, wsB, wsF);
    hipLaunchKernelGGL(capnn_mfma, dim3(gridMain), dim3(NTHREADS), 0, stream,
                       inp, b1, b2, b3, b4, W4,
                       lgr, lcc, lil, imean, istd, tmean, tstd,
                       wsB, wsF, (float*)d_out, N);
}